// Round 9
// baseline (441.469 us; speedup 1.0000x reference)
//
#include <hip/hip_runtime.h>
#include <cstdint>
#include <cstddef>

#define EPS 1e-5f

typedef float    f4    __attribute__((ext_vector_type(4)));
typedef _Float16 half8 __attribute__((ext_vector_type(8)));
typedef _Float16 half4 __attribute__((ext_vector_type(4)));

#define S_XS 33
#define LOG2E 1.44269504088896f

#define GLD_LDS16(gp, lp)                                        \
    __builtin_amdgcn_global_load_lds(                            \
        (const __attribute__((address_space(1))) void*)(gp),     \
        (__attribute__((address_space(3))) void*)(lp), 16, 0, 0)

// raw-rate transcendentals (v_exp_f32 / v_rcp_f32 / v_rsq_f32)
__device__ __forceinline__ float fexp(float x)  { return __builtin_amdgcn_exp2f(x * LOG2E); }
__device__ __forceinline__ float frcp(float x)  { return __builtin_amdgcn_rcpf(x); }
__device__ __forceinline__ float frsq(float x)  { return __builtin_amdgcn_rsqf(x); }
__device__ __forceinline__ float fsig(float g)  { return frcp(1.f + __builtin_amdgcn_exp2f(g * -LOG2E)); }
__device__ __forceinline__ float felu(float t)  { return t > 0.f ? t : fexp(t) - 1.f; }

// ---------------- K_prep: conv (blocks 0..511) + weight-GRN (512..767) ----
// conv: f_fc2_w fp32 -> fp16, layout [f][kq][q][g][j8] (64 KB contiguous per
// f; quarter-major makes k_main's B-frag ds_read_b128 conflict-free).
__global__ __launch_bounds__(256) void k_prep(
    const float* __restrict__ in_w2, _Float16* __restrict__ w2c,
    const float* __restrict__ x, const float* __restrict__ w1,
    const float* __restrict__ b1, const float* __restrict__ w2,
    const float* __restrict__ b2, const float* __restrict__ lng,
    const float* __restrict__ lnb,
    float* __restrict__ x_t, float* __restrict__ wts_t)
{
    __shared__ float w1s[32 * S_XS];
    __shared__ float w2s[64 * S_XS];
    __shared__ float xsW[32 * S_XS];
    __shared__ float ytile[32 * S_XS];

    const int bid = blockIdx.x;
    const int tid = threadIdx.x;

    if (bid < 512) {   // ---- conv path ----
        int t = bid * 256 + tid;
        int q  = t & 3;
        int g  = (t >> 2) & 255;
        int fk = t >> 10;                   // f*4 + kq
        int f = fk >> 2, kq = fk & 3;
        const float* ip = in_w2 + ((size_t)f * 256 + g) * 128 + kq * 32 + q * 8;
        f4 v0 = *(const f4*)ip, v1 = *(const f4*)(ip + 4);
        half8 h;
        #pragma unroll
        for (int i = 0; i < 4; ++i) { h[i] = (_Float16)v0[i]; h[4 + i] = (_Float16)v1[i]; }
        *(half8*)(w2c + (size_t)fk * 8192 + q * 2048 + g * 8) = h;
        return;
    }

    // ---- weight-GRN path ----
    const int lane = tid & 63;
    const int f = lane & 31;
    const int wv = tid >> 6;
    const int row0 = (bid - 512) * 32;

    for (int i = tid; i < 1024; i += 256) {
        int r = i >> 5, c = i & 31;
        w1s[r * S_XS + c] = w1[i];
        xsW[r * S_XS + c] = x[(size_t)row0 * 32 + i];
    }
    for (int i = tid; i < 2048; i += 256) {
        int r = i >> 5, c = i & 31;
        w2s[r * S_XS + c] = w2[i];
    }
    const float b1f = b1[f], b2a = b2[f], b2g = b2[f + 32];
    const float lgf = lng[f], lbf = lnb[f];
    __syncthreads();

    for (int rr = 0; rr < 8; ++rr) {
        const int r = wv * 8 + rr;
        float acc = b1f;
        #pragma unroll
        for (int k = 0; k < 32; ++k)
            acc = fmaf(w1s[f * S_XS + k], xsW[r * S_XS + k], acc);
        float hval = felu(acc);

        float a = b2a, g = b2g;
        #pragma unroll
        for (int k = 0; k < 32; ++k) {
            float hk = __shfl(hval, k, 64);
            a = fmaf(w2s[f * S_XS + k], hk, a);
            g = fmaf(w2s[(f + 32) * S_XS + k], hk, g);
        }
        float xv = xsW[r * S_XS + f];
        float v = xv + a * fsig(g);

        float s = v;
        #pragma unroll
        for (int o = 1; o < 64; o <<= 1) s += __shfl_xor(s, o, 64);
        float mu = s * (1.f / 64.f);
        float d = v - mu;
        float sq = d * d;
        #pragma unroll
        for (int o = 1; o < 64; o <<= 1) sq += __shfl_xor(sq, o, 64);
        float y = d * frsq(sq * (1.f / 64.f) + EPS) * lgf + lbf;

        float m = y;
        #pragma unroll
        for (int o = 1; o < 64; o <<= 1) m = fmaxf(m, __shfl_xor(m, o, 64));
        float e = fexp(y - m);
        float se = e;
        #pragma unroll
        for (int o = 1; o < 64; o <<= 1) se += __shfl_xor(se, o, 64);
        if (lane < 32) ytile[r * S_XS + f] = e * 2.f * frcp(se);
    }
    __syncthreads();
    for (int i = tid; i < 1024; i += 256) {
        int ff = i >> 5, r = i & 31;
        x_t[(size_t)ff * 8192 + row0 + r]   = xsW[r * S_XS + ff];
        wts_t[(size_t)ff * 8192 + row0 + r] = ytile[r * S_XS + ff];
    }
}

// ---------------- K_main: persistent-f fused GRN, zero steady-state barriers ----
// Block = one f x 512 rows (grid 512 = 32 f x 16 tiles, 2 blocks/CU).
// W2[f] (64 KB, exactly half the LDS) staged ONCE via global_load_lds;
// per-f epilogue constants live in registers; each wave free-runs 8x
// 16-row tiles with NO barriers after the first -> MFMA/LDS/VALU overlap
// is pipe-limited, not barrier-limited (rounds 2/4/8: the per-chunk
// barrier + vmcnt(0) drain capped three different stagings at ~80-90 us).
// Output: fp16 partials part[f][h][row], packed 8 B stores; each 128 B
// line is completed by 4 consecutive its of the same wave.
__global__ __launch_bounds__(256, 2) void k_main(
    const _Float16* __restrict__ w2c,   // [32][4][4][256][8] fp16
    const float* __restrict__ x_t,      // [32][8192]
    const float* __restrict__ wts_t,    // [32][8192]
    const float* __restrict__ fc1w, const float* __restrict__ fc1b,
    const float* __restrict__ fc2b,
    const float* __restrict__ skw, const float* __restrict__ skb,
    const float* __restrict__ lng, const float* __restrict__ lnb,
    _Float16* __restrict__ part)        // [32][128][8192] fp16
{
    __shared__ __align__(16) _Float16 w2s[4 * 8192];   // 64 KB

    const int tid = threadIdx.x;
    const int f = blockIdx.x & 31;
    const int tile = blockIdx.x >> 5;
    const int row0 = tile * 512;

    const _Float16* wsrc = w2c + (size_t)f * 32768;
    #pragma unroll
    for (int i = 0; i < 16; ++i)
        GLD_LDS16(wsrc + (i * 256 + tid) * 8, &w2s[(i * 256 + tid) * 8]);

    const int lane = tid & 63;
    const int wv = tid >> 6;
    const int l15 = lane & 15;
    const int q = lane >> 4;
    const int boff = q * 2048 + l15 * 8;

    // per-f epilogue constants in registers (48 VGPR); w1/b1 A-frag params
    // are re-read per tile from L1 to keep VGPR < 200 (no spill).
    float ba[8], bg[8], swv[8], sbv[8], lgv[8], lbv[8];
    #pragma unroll
    for (int nt = 0; nt < 8; ++nt) {
        const int h = nt * 16 + l15;
        ba[nt]  = fc2b[f * 256 + h];
        bg[nt]  = fc2b[f * 256 + 128 + h];
        swv[nt] = skw[f * 128 + h];
        sbv[nt] = skb[f * 128 + h];
        lgv[nt] = lng[f * 128 + h];
        lbv[nt] = lnb[f * 128 + h];
    }
    const float* xcol = x_t + (size_t)f * 8192 + row0 + wv * 128;
    const float* wcol = wts_t + (size_t)f * 8192 + row0 + wv * 128;
    _Float16* pcol = part + ((size_t)f << 20) + row0 + wv * 128;

    __syncthreads();   // the only barrier: W2[f] resident

    for (int it = 0; it < 8; ++it) {
        const int rb = it * 16;
        const float xvA = xcol[rb + l15];

        // A-frags: hv for row (rb + l15), in-lane; w1/b1 from L1
        half8 A[4];
        #pragma unroll
        for (int kq = 0; kq < 4; ++kq) {
            const float* wp = fc1w + f * 128 + kq * 32 + 8 * q;
            const float* bp = fc1b + f * 128 + kq * 32 + 8 * q;
            f4 w0 = *(const f4*)wp, w1v = *(const f4*)(wp + 4);
            f4 b0 = *(const f4*)bp, b1v = *(const f4*)(bp + 4);
            #pragma unroll
            for (int j = 0; j < 4; ++j) {
                A[kq][j]     = (_Float16)felu(fmaf(xvA, w0[j], b0[j]));
                A[kq][4 + j] = (_Float16)felu(fmaf(xvA, w1v[j], b1v[j]));
            }
        }

        // MFMA: bias-initialized accumulators, 4 kq x 16 nt
        f4 acc[16];
        #pragma unroll
        for (int nt = 0; nt < 8; ++nt)
            #pragma unroll
            for (int rg = 0; rg < 4; ++rg) { acc[nt][rg] = ba[nt]; acc[nt + 8][rg] = bg[nt]; }
        #pragma unroll
        for (int kq = 0; kq < 4; ++kq) {
            const _Float16* bb = &w2s[kq * 8192 + boff];
            #pragma unroll
            for (int nt = 0; nt < 16; ++nt) {
                half8 B = *(const half8*)(bb + nt * 128);
                acc[nt] = __builtin_amdgcn_mfma_f32_16x16x32_f16(A[kq], B, acc[nt], 0, 0, 0);
            }
        }

        // GLU + skip; per-row sums in-lane over nt
        f4 xr = *(const f4*)(xcol + rb + 4 * q);
        f4 wr = *(const f4*)(wcol + rb + 4 * q);
        float s[4] = {0.f, 0.f, 0.f, 0.f}, sq[4] = {0.f, 0.f, 0.f, 0.f};
        #pragma unroll
        for (int nt = 0; nt < 8; ++nt) {
            #pragma unroll
            for (int rg = 0; rg < 4; ++rg) {
                float val = fmaf(xr[rg], swv[nt], sbv[nt])
                          + acc[nt][rg] * fsig(acc[nt + 8][rg]);
                acc[nt][rg] = val;
                s[rg] += val;
                sq[rg] = fmaf(val, val, sq[rg]);
            }
        }
        #pragma unroll
        for (int o = 1; o < 16; o <<= 1) {
            #pragma unroll
            for (int rg = 0; rg < 4; ++rg) {
                s[rg] += __shfl_xor(s[rg], o, 64);
                sq[rg] += __shfl_xor(sq[rg], o, 64);
            }
        }
        float mu[4], c1[4];
        #pragma unroll
        for (int rg = 0; rg < 4; ++rg) {
            mu[rg] = s[rg] * (1.f / 128.f);
            float var = sq[rg] * (1.f / 128.f) - mu[rg] * mu[rg];
            c1[rg] = wr[rg] * frsq(fmaxf(var, 0.f) + EPS);
        }

        // LN + weight, packed fp16 partial store: part[f][h][rb + 4q .. +3]
        #pragma unroll
        for (int nt = 0; nt < 8; ++nt) {
            half4 pk;
            #pragma unroll
            for (int rg = 0; rg < 4; ++rg)
                pk[rg] = (_Float16)fmaf((acc[nt][rg] - mu[rg]) * c1[rg], lgv[nt],
                                        wr[rg] * lbv[nt]);
            *(half4*)(pcol + ((size_t)(nt * 16 + l15) << 13) + rb + 4 * q) = pk;
        }
    }
}

// ---------------- K_reduce: out[row][h] = sum_f part[f][h][row] ----------------
// 512 blocks x 16 rows. Reads are row-contiguous 16 B vectors; out written
// coalesced via a small LDS transpose.
__global__ __launch_bounds__(256) void k_reduce(const _Float16* __restrict__ part,
                                                float* __restrict__ out) {
    __shared__ float t[16 * 129];   // 8256 B
    const int tid = threadIdx.x;
    const int row0 = blockIdx.x * 16;
    const int h = tid >> 1;
    const int rbase = (tid & 1) * 8;

    float acc[8] = {0.f, 0.f, 0.f, 0.f, 0.f, 0.f, 0.f, 0.f};
    #pragma unroll
    for (int fq = 0; fq < 32; ++fq) {
        half8 v = *(const half8*)(part + (((size_t)fq * 128 + h) << 13) + row0 + rbase);
        #pragma unroll
        for (int j = 0; j < 8; ++j) acc[j] += (float)v[j];
    }
    #pragma unroll
    for (int i = 0; i < 8; ++i) t[(rbase + i) * 129 + h] = acc[i];
    __syncthreads();
    const int hw = (tid & 31) * 4;
    const int r0 = tid >> 5;   // 0..7
    #pragma unroll
    for (int p2 = 0; p2 < 2; ++p2) {
        const int row = p2 * 8 + r0;
        f4 o;
        #pragma unroll
        for (int j = 0; j < 4; ++j) o[j] = t[row * 129 + hw + j];
        *(f4*)(out + (size_t)(row0 + row) * 128 + hw) = o;
    }
}

extern "C" void kernel_launch(void* const* d_in, const int* in_sizes, int n_in,
                              void* d_out, int out_size, void* d_ws, size_t ws_size,
                              hipStream_t stream) {
    const float* x     = (const float*)d_in[0];
    const float* wg1w  = (const float*)d_in[1];
    const float* wg1b  = (const float*)d_in[2];
    const float* wg2w  = (const float*)d_in[3];
    const float* wg2b  = (const float*)d_in[4];
    const float* wglng = (const float*)d_in[5];
    const float* wglnb = (const float*)d_in[6];
    const float* fc1w  = (const float*)d_in[7];
    const float* fc1b  = (const float*)d_in[8];
    const float* fc2w  = (const float*)d_in[9];
    const float* fc2b  = (const float*)d_in[10];
    const float* skw   = (const float*)d_in[11];
    const float* skb   = (const float*)d_in[12];
    const float* lng   = (const float*)d_in[13];
    const float* lnb   = (const float*)d_in[14];
    float* out = (float*)d_out;

    char* ws = (char*)d_ws;
    _Float16* w2c  = (_Float16*)ws;                 // 2 MB chunked fp16 W2
    float* x_t     = (float*)(ws + (2u << 20));     // 1 MB x transposed [f][row]
    float* wts_t   = (float*)(ws + (3u << 20));     // 1 MB weights transposed
    _Float16* part = (_Float16*)(ws + (4u << 20));  // 64 MB fp16 partials
    // ws_size >= 68 MB verified in round 5 (fast path executed)

    k_prep<<<dim3(768), dim3(256), 0, stream>>>(fc2w, w2c, x, wg1w, wg1b,
                                                wg2w, wg2b, wglng, wglnb,
                                                x_t, wts_t);
    k_main<<<dim3(512), dim3(256), 0, stream>>>(w2c, x_t, wts_t, fc1w, fc1b,
                                                fc2b, skw, skb, lng, lnb, part);
    k_reduce<<<dim3(512), dim3(256), 0, stream>>>(part, out);
}

// Round 12
// 164.815 us; speedup vs baseline: 2.6786x; 2.6786x over previous
//
#include <hip/hip_runtime.h>
#include <cstdint>
#include <cstddef>

#define EPS 1e-5f

typedef float    f4    __attribute__((ext_vector_type(4)));
typedef _Float16 half8 __attribute__((ext_vector_type(8)));
typedef _Float16 half4 __attribute__((ext_vector_type(4)));

#define S_XS 33
#define LOG2E 1.44269504088896f

#define GLD_LDS16(gp, lp)                                        \
    __builtin_amdgcn_global_load_lds(                            \
        (const __attribute__((address_space(1))) void*)(gp),     \
        (__attribute__((address_space(3))) void*)(lp), 16, 0, 0)

// raw-rate transcendentals (v_exp_f32 / v_rcp_f32 / v_rsq_f32)
__device__ __forceinline__ float fexp(float x)  { return __builtin_amdgcn_exp2f(x * LOG2E); }
__device__ __forceinline__ float frcp(float x)  { return __builtin_amdgcn_rcpf(x); }
__device__ __forceinline__ float frsq(float x)  { return __builtin_amdgcn_rsqf(x); }
__device__ __forceinline__ float fsig(float g)  { return frcp(1.f + __builtin_amdgcn_exp2f(g * -LOG2E)); }
__device__ __forceinline__ float felu(float t)  { return t > 0.f ? t : fexp(t) - 1.f; }

// ---- K_prep: conv (blocks 0..511) + weight-GRN (512..767)  [round-8 verbatim]
// conv: f_fc2_w fp32 -> fp16, chunk layout [f][kq][q][g][j8] (16 KB per (f,kq)).
__global__ __launch_bounds__(256) void k_prep(
    const float* __restrict__ in_w2, _Float16* __restrict__ w2c,
    const float* __restrict__ x, const float* __restrict__ w1,
    const float* __restrict__ b1, const float* __restrict__ w2,
    const float* __restrict__ b2, const float* __restrict__ lng,
    const float* __restrict__ lnb,
    float* __restrict__ x_t, float* __restrict__ wts_t)
{
    __shared__ float w1s[32 * S_XS];
    __shared__ float w2s[64 * S_XS];
    __shared__ float xsW[32 * S_XS];
    __shared__ float ytile[32 * S_XS];

    const int bid = blockIdx.x;
    const int tid = threadIdx.x;

    if (bid < 512) {   // ---- conv path ----
        int t = bid * 256 + tid;
        int q  = t & 3;
        int g  = (t >> 2) & 255;
        int fk = t >> 10;                   // f*4 + kq
        int f = fk >> 2, kq = fk & 3;
        const float* ip = in_w2 + ((size_t)f * 256 + g) * 128 + kq * 32 + q * 8;
        f4 v0 = *(const f4*)ip, v1 = *(const f4*)(ip + 4);
        half8 h;
        #pragma unroll
        for (int i = 0; i < 4; ++i) { h[i] = (_Float16)v0[i]; h[4 + i] = (_Float16)v1[i]; }
        *(half8*)(w2c + (size_t)fk * 8192 + q * 2048 + g * 8) = h;
        return;
    }

    // ---- weight-GRN path ----
    const int lane = tid & 63;
    const int f = lane & 31;
    const int wv = tid >> 6;
    const int row0 = (bid - 512) * 32;

    for (int i = tid; i < 1024; i += 256) {
        int r = i >> 5, c = i & 31;
        w1s[r * S_XS + c] = w1[i];
        xsW[r * S_XS + c] = x[(size_t)row0 * 32 + i];
    }
    for (int i = tid; i < 2048; i += 256) {
        int r = i >> 5, c = i & 31;
        w2s[r * S_XS + c] = w2[i];
    }
    const float b1f = b1[f], b2a = b2[f], b2g = b2[f + 32];
    const float lgf = lng[f], lbf = lnb[f];
    __syncthreads();

    for (int rr = 0; rr < 8; ++rr) {
        const int r = wv * 8 + rr;
        float acc = b1f;
        #pragma unroll
        for (int k = 0; k < 32; ++k)
            acc = fmaf(w1s[f * S_XS + k], xsW[r * S_XS + k], acc);
        float hval = felu(acc);

        float a = b2a, g = b2g;
        #pragma unroll
        for (int k = 0; k < 32; ++k) {
            float hk = __shfl(hval, k, 64);
            a = fmaf(w2s[f * S_XS + k], hk, a);
            g = fmaf(w2s[(f + 32) * S_XS + k], hk, g);
        }
        float xv = xsW[r * S_XS + f];
        float v = xv + a * fsig(g);

        float s = v;
        #pragma unroll
        for (int o = 1; o < 64; o <<= 1) s += __shfl_xor(s, o, 64);
        float mu = s * (1.f / 64.f);
        float d = v - mu;
        float sq = d * d;
        #pragma unroll
        for (int o = 1; o < 64; o <<= 1) sq += __shfl_xor(sq, o, 64);
        float y = d * frsq(sq * (1.f / 64.f) + EPS) * lgf + lbf;

        float m = y;
        #pragma unroll
        for (int o = 1; o < 64; o <<= 1) m = fmaxf(m, __shfl_xor(m, o, 64));
        float e = fexp(y - m);
        float se = e;
        #pragma unroll
        for (int o = 1; o < 64; o <<= 1) se += __shfl_xor(se, o, 64);
        if (lane < 32) ytile[r * S_XS + f] = e * 2.f * frcp(se);
    }
    __syncthreads();
    for (int i = tid; i < 1024; i += 256) {
        int ff = i >> 5, r = i & 31;
        x_t[(size_t)ff * 8192 + row0 + r]   = xsW[r * S_XS + ff];
        wts_t[(size_t)ff * 8192 + row0 + r] = ytile[r * S_XS + ff];
    }
}

// ---------------- K_main: round-8 skeleton + round-9-proven dataflow opts ----
// Block = 64 rows x 4 features; wave wv owns rows [16wv,16wv+16) x all 256 g.
// Staging loop / epilogue / atomics: round-8 verbatim (known-good).
// Only deltas (both correctness-proven in round 9's k_main):
//   (1) A-frags for all 4 kq computed at f-start (batched loads, one elu chain)
//   (2) ba/bg loaded at f-start, folded into MFMA acc init (dead after init).
// The ep pre-transpose table (rounds 10/11) is ABANDONED: failed twice with
// absmax ~0.68, resisted three paper audits.
__global__ __launch_bounds__(256, 3) void k_main(
    const _Float16* __restrict__ w2c,   // [32][4][4][256][8] fp16 chunks
    const float* __restrict__ x_t,      // [32][8192]
    const float* __restrict__ wts_t,    // [32][8192]
    const float* __restrict__ fc1w, const float* __restrict__ fc1b,
    const float* __restrict__ fc2b,
    const float* __restrict__ skw, const float* __restrict__ skb,
    const float* __restrict__ lng, const float* __restrict__ lnb,
    float* __restrict__ out)            // [8192][128], pre-zeroed
{
    __shared__ __align__(16) _Float16 bchunk[2][8192];   // 32 KB total

    const int tid = threadIdx.x;
    const int fbase = (blockIdx.x >> 7) * 4;
    const int row0 = (blockIdx.x & 127) * 64;

    const int lane = tid & 63;
    const int wv = tid >> 6;
    const int l15 = lane & 15;
    const int q = lane >> 4;
    const int boff = q * 2048 + l15 * 8;   // swizzled B-frag base (halves)

    auto stage = [&](int c) {
        const _Float16* gp = w2c + ((size_t)(fbase + (c >> 2)) * 4 + (c & 3)) * 8192;
        #pragma unroll
        for (int r = 0; r < 4; ++r)
            GLD_LDS16(gp + (r * 256 + tid) * 8,
                      &bchunk[c & 1][(r * 256 + tid) * 8]);
    };

    float out_acc[8][4];
    #pragma unroll
    for (int nt = 0; nt < 8; ++nt)
        #pragma unroll
        for (int rg = 0; rg < 4; ++rg) out_acc[nt][rg] = 0.f;

    stage(0);
    __syncthreads();   // chunk 0 resident

    int c = 0;
    for (int fi = 0; fi < 4; ++fi) {
        const int f = fbase + fi;
        const float* xcol = x_t + (size_t)f * 8192 + row0 + wv * 16;
        const float* wcol = wts_t + (size_t)f * 8192 + row0 + wv * 16;
        const float xvA = xcol[l15];

        // (1) A-frags for all 4 kq at f-start (proven in round 9)
        half8 A[4];
        #pragma unroll
        for (int kq = 0; kq < 4; ++kq) {
            const float* wp = fc1w + f * 128 + kq * 32 + 8 * q;
            const float* bp = fc1b + f * 128 + kq * 32 + 8 * q;
            f4 w0 = *(const f4*)wp, w1v = *(const f4*)(wp + 4);
            f4 b0 = *(const f4*)bp, b1v = *(const f4*)(bp + 4);
            #pragma unroll
            for (int j = 0; j < 4; ++j) {
                A[kq][j]     = (_Float16)felu(fmaf(xvA, w0[j], b0[j]));
                A[kq][4 + j] = (_Float16)felu(fmaf(xvA, w1v[j], b1v[j]));
            }
        }

        // (2) bias-fold: acc init from ba/bg scalar loads (proven in round 9)
        f4 acc[16];
        #pragma unroll
        for (int nt = 0; nt < 8; ++nt) {
            const int h = nt * 16 + l15;
            float ba = fc2b[f * 256 + h];
            float bg = fc2b[f * 256 + 128 + h];
            #pragma unroll
            for (int rg = 0; rg < 4; ++rg) { acc[nt][rg] = ba; acc[nt + 8][rg] = bg; }
        }

        #pragma unroll
        for (int kq = 0; kq < 4; ++kq, ++c) {
            if (c + 1 < 16) stage(c + 1);
            const _Float16* bb = &bchunk[c & 1][boff];
            #pragma unroll
            for (int nt = 0; nt < 16; ++nt) {
                half8 B = *(const half8*)(bb + nt * 128);   // [q][g=nt*16+l15][j]
                acc[nt] = __builtin_amdgcn_mfma_f32_16x16x32_f16(A[kq], B, acc[nt], 0, 0, 0);
            }
            __syncthreads();   // chunk c consumed everywhere; stage(c+1) drained
        }

        // ---- epilogue: round-8 verbatim (scalar param loads in place) ----
        f4 xr = *(const f4*)(xcol + 4 * q);
        f4 wr = *(const f4*)(wcol + 4 * q);
        float s[4] = {0.f, 0.f, 0.f, 0.f}, sq[4] = {0.f, 0.f, 0.f, 0.f};
        #pragma unroll
        for (int nt = 0; nt < 8; ++nt) {
            const int h = nt * 16 + l15;
            float sw = skw[f * 128 + h];
            float sb = skb[f * 128 + h];
            #pragma unroll
            for (int rg = 0; rg < 4; ++rg) {
                float a = acc[nt][rg];              // ba folded into init
                float g = acc[nt + 8][rg];          // bg folded into init
                float val = fmaf(xr[rg], sw, sb) + a * fsig(g);
                acc[nt][rg] = val;
                s[rg] += val;
                sq[rg] = fmaf(val, val, sq[rg]);
            }
        }
        #pragma unroll
        for (int o = 1; o < 16; o <<= 1) {
            #pragma unroll
            for (int rg = 0; rg < 4; ++rg) {
                s[rg] += __shfl_xor(s[rg], o, 64);
                sq[rg] += __shfl_xor(sq[rg], o, 64);
            }
        }
        float mu[4], c1[4];
        #pragma unroll
        for (int rg = 0; rg < 4; ++rg) {
            mu[rg] = s[rg] * (1.f / 128.f);
            float var = sq[rg] * (1.f / 128.f) - mu[rg] * mu[rg];
            c1[rg] = wr[rg] * frsq(fmaxf(var, 0.f) + EPS);
        }
        #pragma unroll
        for (int nt = 0; nt < 8; ++nt) {
            const int h = nt * 16 + l15;
            float lg = lng[f * 128 + h];
            float lb = lnb[f * 128 + h];
            #pragma unroll
            for (int rg = 0; rg < 4; ++rg) {
                float u = (acc[nt][rg] - mu[rg]) * c1[rg];
                out_acc[nt][rg] = fmaf(u, lg, fmaf(wr[rg], lb, out_acc[nt][rg]));
            }
        }
    }

    // ---- single atomic combine pass (8 partial adds per element total) ----
    #pragma unroll
    for (int nt = 0; nt < 8; ++nt) {
        #pragma unroll
        for (int rg = 0; rg < 4; ++rg) {
            const int r = row0 + wv * 16 + 4 * q + rg;
            atomicAdd(&out[(size_t)r * 128 + nt * 16 + l15], out_acc[nt][rg]);
        }
    }
}

extern "C" void kernel_launch(void* const* d_in, const int* in_sizes, int n_in,
                              void* d_out, int out_size, void* d_ws, size_t ws_size,
                              hipStream_t stream) {
    const float* x     = (const float*)d_in[0];
    const float* wg1w  = (const float*)d_in[1];
    const float* wg1b  = (const float*)d_in[2];
    const float* wg2w  = (const float*)d_in[3];
    const float* wg2b  = (const float*)d_in[4];
    const float* wglng = (const float*)d_in[5];
    const float* wglnb = (const float*)d_in[6];
    const float* fc1w  = (const float*)d_in[7];
    const float* fc1b  = (const float*)d_in[8];
    const float* fc2w  = (const float*)d_in[9];
    const float* fc2b  = (const float*)d_in[10];
    const float* skw   = (const float*)d_in[11];
    const float* skb   = (const float*)d_in[12];
    const float* lng   = (const float*)d_in[13];
    const float* lnb   = (const float*)d_in[14];
    float* out = (float*)d_out;

    char* ws = (char*)d_ws;
    _Float16* w2c = (_Float16*)ws;               // 2 MB chunked fp16 W2
    float* x_t    = (float*)(ws + (2u << 20));   // 1 MB x transposed [f][row]
    float* wts_t  = (float*)(ws + (3u << 20));   // 1 MB weights transposed

    k_prep<<<dim3(768), dim3(256), 0, stream>>>(fc2w, w2c, x, wg1w, wg1b,
                                                wg2w, wg2b, wglng, wglnb,
                                                x_t, wts_t);
    hipMemsetAsync(out, 0, (size_t)out_size * sizeof(float), stream);
    k_main<<<dim3(1024), dim3(256), 0, stream>>>(w2c, x_t, wts_t, fc1w, fc1b,
                                                 fc2b, skw, skb, lng, lnb, out);
}